// Round 8
// baseline (216119.751 us; speedup 1.0000x reference)
//
#include <hip/hip_runtime.h>
#include <math.h>

// HierarchicalRecursiveTRM on MI355X — round 8.
// 8 teams x (2 batches, 32 WGs). Weights f32 in LDS (1/32 rows per WG).
// Exchange: tag-embedded 8B words, but now via atomic RMWs on BOTH sides so
// producer/consumer meet at the MALL atomic units (cache-resident), not DRAM:
//   producer: __hip_atomic_exchange (no-return swap_x2), fire-and-forget
//   consumer: __hip_atomic_fetch_add(p,0) (returning add_x2 = load-at-MALL)
// Round 7 evidence: plain relaxed agent loads/stores traverse DRAM each stage
// (FETCH 14KB + WRITE 30KB per team-stage == the exchange set), flooring the
// stage at ~2.6us. Round 1 measured atomic RMWs at ~220ns.
// Consumer: wave 0 only (compact layout, batched in-flight RMWs), applies the
// elementwise update, broadcasts via LDS barrier. 2 barriers/stage.

#define NB   16
#define SEQ  4096
#define TEAMS 8
#define WPT  32
#define BPT  2
#define NTH  256

typedef unsigned long long u64;

__device__ __forceinline__ float fexp(float v){ return __builtin_amdgcn_exp2f(v*1.44269504089f); }
__device__ __forceinline__ float sigf(float v){ return __builtin_amdgcn_rcpf(1.f + fexp(-v)); }
__device__ __forceinline__ float ftanh(float v){ return 2.f*sigf(2.f*v) - 1.f; }
__device__ __forceinline__ float w2f(u64 w){ return __uint_as_float((unsigned)w); }

__device__ __forceinline__ u64 packw(float v, unsigned tag){
  return ((u64)tag << 32) | (u64)__float_as_uint(v);
}
// producer: no-return atomic swap (executes at coherence-point atomic unit)
__device__ __forceinline__ void putw(u64* p, u64 v){
  (void)__hip_atomic_exchange(p, v, __ATOMIC_RELAXED, __HIP_MEMORY_SCOPE_AGENT);
}
// consumer: returning atomic add(0) == load executed at coherence point
__device__ __forceinline__ u64 getw(u64* p){
  return __hip_atomic_fetch_add(p, 0ull, __ATOMIC_RELAXED, __HIP_MEMORY_SCOPE_AGENT);
}

template<int N>
__device__ __forceinline__ void pollN(u64* p, unsigned tag, u64 (&w)[N]){
  for(;;){
    bool ok = true;
    #pragma unroll
    for (int k=0;k<N;k++)
      w[k] = getw(p+k);            // N independent returning atomics in flight
    #pragma unroll
    for (int k=0;k<N;k++)
      ok = ok && ((unsigned)(w[k]>>32) >= tag);
    if (ok) return;
    __builtin_amdgcn_s_sleep(1);
  }
}

// Raw WG barrier: LDS ordering only, no vmcnt drain (exchange stores fly free).
#define WGBAR() asm volatile("s_waitcnt lgkmcnt(0)\n\ts_barrier" ::: "memory")

extern "C" __global__ __launch_bounds__(NTH, 1)
void trm_kernel(const float* __restrict__ x,   const float* __restrict__ h0,
                const float* __restrict__ wih, const float* __restrict__ whh,
                const float* __restrict__ bih, const float* __restrict__ bhh,
                const float* __restrict__ Lgw, const float* __restrict__ Lgb,
                const float* __restrict__ Ltw, const float* __restrict__ Ltb,
                const float* __restrict__ Luw, const float* __restrict__ Lub,
                const float* __restrict__ Hgw, const float* __restrict__ Hgb,
                const float* __restrict__ Htw, const float* __restrict__ Htb,
                const float* __restrict__ Huw, const float* __restrict__ Hub,
                float* __restrict__ out,
                u64* __restrict__ act_base)
{
  const int team = blockIdx.x & (TEAMS-1);
  const int j    = blockIdx.x / TEAMS;       // 0..31 slice id within team
  const int tid  = threadIdx.x;

  __shared__ float wgRZ[16][520];
  __shared__ float wgX[8][264];
  __shared__ float wgN[8][264];
  __shared__ float wclG[8][520], wclT[8][520];
  __shared__ float wchG[8][520], wchT[8][520];
  __shared__ float wul[8][264],  wuh[8][264];
  __shared__ float xst [BPT][256];
  __shared__ float st_o [BPT][256];
  __shared__ float st_zh[BPT][256];
  __shared__ float st_zl[BPT][256];
  __shared__ float st_h [BPT][256];
  __shared__ float bR[8],bZ[8],bX[8],bN[8],bCLg[8],bCLt[8],bCHg[8],bCHt[8],bUL[8],bUH[8];

  // ---------- one-time weight staging ----------
  {
    const int k = tid;
    for (int r=0;r<8;r++){
      const int nr = j*8+r;
      wgRZ[r][k]       = wih[(size_t)nr*256+k];
      wgRZ[r][256+k]   = whh[(size_t)nr*256+k];
      wgRZ[8+r][k]     = wih[(size_t)(256+nr)*256+k];
      wgRZ[8+r][256+k] = whh[(size_t)(256+nr)*256+k];
      wgX[r][k] = wih[(size_t)(512+nr)*256+k];
      wgN[r][k] = whh[(size_t)(512+nr)*256+k];
      wclG[r][k] = Lgw[(size_t)nr*512+k];  wclG[r][256+k] = Lgw[(size_t)nr*512+256+k];
      wclT[r][k] = Ltw[(size_t)nr*512+k];  wclT[r][256+k] = Ltw[(size_t)nr*512+256+k];
      wchG[r][k] = Hgw[(size_t)nr*512+k];  wchG[r][256+k] = Hgw[(size_t)nr*512+256+k];
      wchT[r][k] = Htw[(size_t)nr*512+k];  wchT[r][256+k] = Htw[(size_t)nr*512+256+k];
      wul[r][k] = Luw[(size_t)nr*256+k];
      wuh[r][k] = Huw[(size_t)nr*256+k];
    }
    if (tid<8){
      const int nr = j*8+tid;
      bR[tid]  = bih[nr]     + bhh[nr];
      bZ[tid]  = bih[256+nr] + bhh[256+nr];
      bX[tid]  = bih[512+nr];
      bN[tid]  = bhh[512+nr];
      bCLg[tid]= Lgb[nr];  bCLt[tid]= Ltb[nr];
      bCHg[tid]= Hgb[nr];  bCHt[tid]= Htb[nr];
      bUL[tid] = Lub[nr];  bUH[tid] = Hub[nr];
    }
    for (int u=tid; u<BPT*256; u+=NTH){
      const int b=u>>8, i=u&255;
      st_h[b][i]  = h0[(team*BPT+b)*256+i];
      st_o[b][i]  = 0.f;
      st_zh[b][i] = 0.f;
      st_zl[b][i] = 0.f;
    }
    // x(0) into xst now; prefetch x(1) after the sync
    xst[0][tid] = x[((size_t)(team*BPT+0)*SEQ + 0)*256 + tid];
    xst[1][tid] = x[((size_t)(team*BPT+1)*SEQ + 0)*256 + tid];
  }
  __syncthreads();

  float px0 = x[((size_t)(team*BPT+0)*SEQ + 1)*256 + tid];   // x(t+1) holder
  float px1 = x[((size_t)(team*BPT+1)*SEQ + 1)*256 + tid];

  u64* actT = act_base + (size_t)team*8192;  // 64KB/team; 2 x 2048-word buffers
  unsigned kst = 0;

  // C-cell: rows [8j,8j+8): u<8 gate rows, u>=8 tanh rows. K=512=[o|hid].
  // Compact words: w = b*512 + n*2 + isT.
  auto cstage = [&](float (*WG)[520], float (*WT)[520], float* bG, float* bT,
                    float (*hid)[256], bool wout, int tt){
    const unsigned tag = kst + 1u;
    u64* buf = actT + (kst & 1u)*2048;
    WGBAR();                                   // prev-stage state updates visible
    const int u = tid>>4, kk = tid&15, r = u&7;
    const bool isT = (u>=8);
    const float* wr = isT? WT[r] : WG[r];
    float a0=0.f, a1=0.f;
    #pragma unroll
    for (int i=0;i<16;i++){
      const float w = wr[kk+16*i];
      a0 += w*st_o[0][kk+16*i];
      a1 += w*st_o[1][kk+16*i];
    }
    #pragma unroll
    for (int i=0;i<16;i++){
      const float w = wr[256+kk+16*i];
      a0 += w*hid[0][kk+16*i];
      a1 += w*hid[1][kk+16*i];
    }
    a0 += __shfl_xor(a0,1); a0 += __shfl_xor(a0,2); a0 += __shfl_xor(a0,4); a0 += __shfl_xor(a0,8);
    a1 += __shfl_xor(a1,1); a1 += __shfl_xor(a1,2); a1 += __shfl_xor(a1,4); a1 += __shfl_xor(a1,8);
    if (kk==0){
      const float bb = isT? bT[r] : bG[r];
      const int n = j*8+r;
      putw(&buf[0*512 + n*2 + (isT?1:0)], packw(a0+bb, tag));
      putw(&buf[1*512 + n*2 + (isT?1:0)], packw(a1+bb, tag));
    }
    WGBAR();                                   // matvec LDS reads done
    if (tid < 64){                             // wave 0: poll + update + broadcast
      const int b = tid>>5, i0 = (tid&31)*8;
      u64 w[16];
      pollN<16>(buf + b*512 + i0*2, tag, w);
      #pragma unroll
      for (int q=0;q<8;q++){
        const int i = i0+q;
        const float g  = sigf(w2f(w[2*q]));
        const float rr = ftanh(w2f(w[2*q+1]));
        const float o  = g*rr + (1.f-g)*st_o[b][i];
        st_o[b][i] = o;
        if (wout) out[((size_t)(team*BPT+b)*SEQ + tt)*256 + i] = o;
      }
    }
    kst++;
  };

  // U-cell: 8 rows/WG, 32-lane units, K=256 over st_o; dst = tanh(pre).
  // Compact words: w = b*256 + n.
  auto ustage = [&](float (*W)[264], float* bU, float (*dst)[256]){
    const unsigned tag = kst + 1u;
    u64* buf = actT + (kst & 1u)*2048;
    WGBAR();
    const int u = tid>>5, kk = tid&31;
    const float* wr = W[u];
    float a0=0.f, a1=0.f;
    #pragma unroll
    for (int i=0;i<8;i++){
      const float w = wr[kk+32*i];
      a0 += w*st_o[0][kk+32*i];
      a1 += w*st_o[1][kk+32*i];
    }
    a0 += __shfl_xor(a0,1); a0 += __shfl_xor(a0,2); a0 += __shfl_xor(a0,4); a0 += __shfl_xor(a0,8); a0 += __shfl_xor(a0,16);
    a1 += __shfl_xor(a1,1); a1 += __shfl_xor(a1,2); a1 += __shfl_xor(a1,4); a1 += __shfl_xor(a1,8); a1 += __shfl_xor(a1,16);
    if (kk==0){
      const int n = j*8+u;
      putw(&buf[0*256 + n], packw(a0+bU[u], tag));
      putw(&buf[1*256 + n], packw(a1+bU[u], tag));
    }
    WGBAR();
    if (tid < 64){
      const int b = tid>>5, i0 = (tid&31)*8;
      u64 w[8];
      pollN<8>(buf + b*256 + i0, tag, w);
      #pragma unroll
      for (int q=0;q<8;q++)
        dst[b][i0+q] = ftanh(w2f(w[q]));
    }
    kst++;
  };

  #pragma unroll 1
  for (int t=0; t<SEQ; ++t){
    // ---- GRU stage. Compact words: w = b*1024 + n*4 + s, s={pr,pz,xn,hn} ----
    {
      const unsigned tag = kst + 1u;
      u64* buf = actT + (kst & 1u)*2048;
      WGBAR();
      const int u = tid>>4, kk = tid&15, r = u&7;
      const int n = j*8+r;
      { // pass1: u<8 r-rows, u>=8 z-rows; K=512=[x|h]
        const bool isZ = (u>=8);
        const float* wr = wgRZ[u];
        float a0=0.f, a1=0.f;
        #pragma unroll
        for (int i=0;i<16;i++){
          const float w = wr[kk+16*i];
          a0 += w*xst[0][kk+16*i];
          a1 += w*xst[1][kk+16*i];
        }
        #pragma unroll
        for (int i=0;i<16;i++){
          const float w = wr[256+kk+16*i];
          a0 += w*st_h[0][kk+16*i];
          a1 += w*st_h[1][kk+16*i];
        }
        a0 += __shfl_xor(a0,1); a0 += __shfl_xor(a0,2); a0 += __shfl_xor(a0,4); a0 += __shfl_xor(a0,8);
        a1 += __shfl_xor(a1,1); a1 += __shfl_xor(a1,2); a1 += __shfl_xor(a1,4); a1 += __shfl_xor(a1,8);
        if (kk==0){
          const float bb = isZ? bZ[r] : bR[r];
          putw(&buf[0*1024 + n*4 + (isZ?1:0)], packw(a0+bb, tag));
          putw(&buf[1*1024 + n*4 + (isZ?1:0)], packw(a1+bb, tag));
        }
      }
      { // pass2: u<8 xn rows (src=x), u>=8 hn rows (src=h); K=256
        const bool isH = (u>=8);
        const float* wr = isH? wgN[r] : wgX[r];
        float (*src)[256] = isH? st_h : xst;
        float a0=0.f, a1=0.f;
        #pragma unroll
        for (int i=0;i<16;i++){
          const float w = wr[kk+16*i];
          a0 += w*src[0][kk+16*i];
          a1 += w*src[1][kk+16*i];
        }
        a0 += __shfl_xor(a0,1); a0 += __shfl_xor(a0,2); a0 += __shfl_xor(a0,4); a0 += __shfl_xor(a0,8);
        a1 += __shfl_xor(a1,1); a1 += __shfl_xor(a1,2); a1 += __shfl_xor(a1,4); a1 += __shfl_xor(a1,8);
        if (kk==0){
          const float bb = isH? bN[r] : bX[r];
          putw(&buf[0*1024 + n*4 + 2 + (isH?1:0)], packw(a0+bb, tag));
          putw(&buf[1*1024 + n*4 + 2 + (isH?1:0)], packw(a1+bb, tag));
        }
      }
      WGBAR();
      // off-critical-path: refill xst with x(t+1), prefetch x(t+2)
      xst[0][tid] = px0;
      xst[1][tid] = px1;
      if (t+2 < SEQ){
        px0 = x[((size_t)(team*BPT+0)*SEQ + (t+2))*256 + tid];
        px1 = x[((size_t)(team*BPT+1)*SEQ + (t+2))*256 + tid];
      }
      if (tid < 64){                            // wave 0: poll + GRU update
        const int b = tid>>5, i0 = (tid&31)*8;
        const bool last = (t==SEQ-1);
        u64 w[16];
        #pragma unroll
        for (int h=0; h<2; h++){
          pollN<16>(buf + b*1024 + (i0+4*h)*4, tag, w);
          #pragma unroll
          for (int q=0;q<4;q++){
            const int i = i0+4*h+q;
            const float rg = sigf(w2f(w[4*q]));
            const float zg = sigf(w2f(w[4*q+1]));
            const float ng = ftanh(w2f(w[4*q+2]) + rg*w2f(w[4*q+3]));
            const float hv = (1.f-zg)*ng + zg*st_h[b][i];
            st_h[b][i] = hv;
            st_o[b][i] = hv;
            if (last) out[(size_t)NB*SEQ*256 + (team*BPT+b)*256 + i] = hv;
          }
        }
      }
      kst++;
    }
    // ---- refinement: 2 H-cycles of (3x L-cell, U_L, H-cell, U_H) ----
    #pragma unroll 1
    for (int c=0;c<2;c++){
      cstage(wclG,wclT,bCLg,bCLt,st_zh,false,t);
      cstage(wclG,wclT,bCLg,bCLt,st_zh,false,t);
      cstage(wclG,wclT,bCLg,bCLt,st_zh,false,t);
      ustage(wul,bUL,st_zl);
      cstage(wchG,wchT,bCHg,bCHt,st_zl,(c==1),t);
      ustage(wuh,bUH,st_zh);
    }
  }
}

extern "C" void kernel_launch(void* const* d_in, const int* in_sizes, int n_in,
                              void* d_out, int out_size, void* d_ws, size_t ws_size,
                              hipStream_t stream)
{
  // ws: tagged act buffers, 64KB per team. Zeroed every launch (tags must
  // start below 1; harness poisons 0xAA).
  hipMemsetAsync(d_ws, 0, (size_t)TEAMS*8192*sizeof(u64), stream);
  u64* act = (u64*)d_ws;

  dim3 grid(TEAMS*WPT), block(NTH);
  hipLaunchKernelGGL(trm_kernel, grid, block, 0, stream,
    (const float*)d_in[0],  (const float*)d_in[1],
    (const float*)d_in[2],  (const float*)d_in[3],
    (const float*)d_in[4],  (const float*)d_in[5],
    (const float*)d_in[6],  (const float*)d_in[7],
    (const float*)d_in[8],  (const float*)d_in[9],
    (const float*)d_in[10], (const float*)d_in[11],
    (const float*)d_in[12], (const float*)d_in[13],
    (const float*)d_in[14], (const float*)d_in[15],
    (const float*)d_in[16], (const float*)d_in[17],
    (float*)d_out, act);
}